// Round 9
// baseline (541.400 us; speedup 1.0000x reference)
//
#include <hip/hip_runtime.h>
#include <math.h>

#define K_ADA 0.1f
#define NEPS 1e-5f

typedef __attribute__((ext_vector_type(8))) short short8;
typedef __attribute__((ext_vector_type(4))) float f32x4;
typedef unsigned short ushort_t;

__device__ __forceinline__ ushort_t f2b(float f) {
    union { float f; unsigned u; } v; v.f = f;
    unsigned r = (v.u + 0x7fffu + ((v.u >> 16) & 1u)) >> 16;
    return (ushort_t)r;
}

__device__ __forceinline__ float wave_sum64(float v) {
#pragma unroll
    for (int m = 1; m < 64; m <<= 1) v += __shfl_xor(v, m, 64);
    return v;
}

// tap -> halo delta (stride-2 input, 9x9 plane): kd*81 + kh*9 + kw; tap 27 pads to 0
__host__ __device__ constexpr int tapd2(int tap) {
    return tap >= 27 ? 0 : (tap / 9) * 81 + ((tap / 3) % 3) * 9 + (tap % 3);
}

// ---- generic pack element: [3,3,3,CIN,COUT] fp32 -> B-fragment bf16 ----
template <int CIN, int COUT>
__device__ __forceinline__ void pack_w_el(const float* __restrict__ w,
                                          ushort_t* __restrict__ wp, int t)
{
    constexpr int NKH = CIN / 32;
    constexpr int NCT = COUT / 16;
    int jj = t & 7;
    int lane = (t >> 3) & 63;
    int rest = t >> 9;              // (tap*NCT + ct)*NKH + kh
    int kh = rest % NKH;
    int rest2 = rest / NKH;
    int ct = rest2 % NCT;
    int tap = rest2 / NCT;
    int cin = kh * 32 + (lane >> 4) * 8 + jj;
    int cout = ct * 16 + (lane & 15);
    wp[t] = f2b(w[(tap * CIN + cin) * COUT + cout]);
}

// ---- merged prep: pack w1..w5 + dmask m1->m2 + zero-pad + counter, one launch ----
__global__ __launch_bounds__(256) void prep_k(
    const float* __restrict__ w1, const float* __restrict__ w2,
    const float* __restrict__ w3, const float* __restrict__ w4,
    const float* __restrict__ w5, const float* __restrict__ m1,
    ushort_t* __restrict__ wp1, ushort_t* __restrict__ wp2,
    ushort_t* __restrict__ wp3, ushort_t* __restrict__ wp4,
    ushort_t* __restrict__ wp5, float* __restrict__ m2,
    float* __restrict__ zeropad, int* __restrict__ counter)
{
    int t = blockIdx.x * 256 + threadIdx.x;
    if (t < 512) {
        // w1 [27][1][16] -> single frag, K=taps (pad 32)
        int jj = t & 7;
        int lane = t >> 3;
        int tap = (lane >> 4) * 8 + jj;
        int cout = lane & 15;
        wp1[t] = (tap < 27) ? f2b(w1[tap * 16 + cout]) : (ushort_t)0;
    } else if (t < 14848) {
        // w2 [27][16][32] -> tap-paired frags: 14 pairs x 2 ct
        int u = t - 512;
        int jj = u & 7;
        int lane = (u >> 3) & 63;
        int rest = u >> 9;
        int ct = rest & 1;
        int p = rest >> 1;
        int tap = 2 * p + (lane >> 5);
        int cin = ((lane >> 4) & 1) * 8 + jj;
        int cout = ct * 16 + (lane & 15);
        wp2[u] = (tap < 27) ? f2b(w2[(tap * 16 + cin) * 32 + cout]) : (ushort_t)0;
    } else if (t < 42496) {
        pack_w_el<32, 32>(w3, wp3, t - 14848);
    } else if (t < 97792) {
        pack_w_el<32, 64>(w4, wp4, t - 42496);
    } else if (t < 208384) {
        pack_w_el<64, 64>(w5, wp5, t - 97792);
    } else if (t < 429568) {
        // dmask 96 -> 48
        int v = t - 208384;
        constexpr int GO = 48, GI = 96;
        int b = v / (GO * GO * GO);
        int r = v % (GO * GO * GO);
        int d = r / (GO * GO), h = (r / GO) % GO, x = r % GO;
        float mx = 0.f;
        for (int kd = 0; kd < 3; ++kd) {
            int zd = 2 * d + kd - 1; if ((unsigned)zd >= GI) continue;
            for (int kh = 0; kh < 3; ++kh) {
                int zh = 2 * h + kh - 1; if ((unsigned)zh >= GI) continue;
                for (int kw = 0; kw < 3; ++kw) {
                    int zx = 2 * x + kw - 1; if ((unsigned)zx >= GI) continue;
                    mx = fmaxf(mx, m1[((b * GI + zd) * GI + zh) * GI + zx]);
                }
            }
        }
        m2[v] = mx;
    } else if (t < 429576) {
        zeropad[t - 429568] = 0.f;  // 32B zero block for OOB load redirection
    } else if (t == 429576) {
        *counter = 0;               // active-voxel list counter
    }
}

// downsample mask: max over 3^3 window, stride 2, pad 1 (m2 -> m3)
template <int GO, int GI>
__global__ __launch_bounds__(256) void dmask_k(const float* __restrict__ mi,
                                               float* __restrict__ mo)
{
    constexpr int N = 2 * GO * GO * GO;
    int v = blockIdx.x * 256 + threadIdx.x;
    if (v >= N) return;
    int b = v / (GO * GO * GO);
    int r = v % (GO * GO * GO);
    int d = r / (GO * GO), h = (r / GO) % GO, x = r % GO;
    float mx = 0.f;
    for (int kd = 0; kd < 3; ++kd) {
        int zd = 2 * d + kd - 1; if ((unsigned)zd >= GI) continue;
        for (int kh = 0; kh < 3; ++kh) {
            int zh = 2 * h + kh - 1; if ((unsigned)zh >= GI) continue;
            for (int kw = 0; kw < 3; ++kw) {
                int zx = 2 * x + kw - 1; if ((unsigned)zx >= GI) continue;
                mx = fmaxf(mx, mi[((b * GI + zd) * GI + zh) * GI + zx]);
            }
        }
    }
    mo[v] = mx;
}

// ---- conv1 stage A: zero-fill h1b dense + compact active voxel list ----
__global__ __launch_bounds__(256) void conv1_fill_k(const float* __restrict__ m1,
                                                    ushort_t* __restrict__ h1b,
                                                    int* __restrict__ list,
                                                    int* __restrict__ counter)
{
    int v = blockIdx.x * 256 + threadIdx.x;  // grid covers exactly 2*96^3
    const short8 z = {0, 0, 0, 0, 0, 0, 0, 0};
    short8* hp = reinterpret_cast<short8*>(h1b + (size_t)v * 16);
    hp[0] = z; hp[1] = z;
    bool act = (m1[v] != 0.f);
    unsigned long long msk = __ballot(act);
    int lane = threadIdx.x & 63;
    int base = 0;
    int cnt = __popcll(msk);
    if (lane == 0 && cnt) base = atomicAdd(counter, cnt);
    base = __shfl(base, 0, 64);
    if (act) {
        int pre = __popcll(msk & ((1ull << lane) - 1ull));
        list[base + pre] = v;
    }
}

// ---- conv1 stage B: MFMA over ACTIVE voxels only (16 per wave, grid-stride) ----
__global__ __launch_bounds__(256) void conv1_act_k(const float* __restrict__ x,
                                                   const int* __restrict__ list,
                                                   const int* __restrict__ counter,
                                                   const ushort_t* __restrict__ wp1,
                                                   const float* __restrict__ bias,
                                                   const float* __restrict__ gain,
                                                   const float* __restrict__ zerof,
                                                   ushort_t* __restrict__ h1b)
{
    constexpr int G = 96, G3 = G * G * G;
    int nact = counter[0];
    if (nact <= 0) return;
    int gwave = (blockIdx.x * 256 + threadIdx.x) >> 6;
    int nwaves = gridDim.x * 4;
    int lane = threadIdx.x & 63;
    int m = lane & 15, q = lane >> 4;
    int nchunk = (nact + 15) >> 4;
    float bn = bias[m], gn = gain[m];
    short8 bfr = *reinterpret_cast<const short8*>(wp1 + lane * 8);

    for (int chunk = gwave; chunk < nchunk; chunk += nwaves) {
        int idx = chunk * 16 + m;
        int vm = list[min(idx, nact - 1)];
        int b = vm / G3;
        int rr = vm % G3;
        int dm = rr / (G * G), hm = (rr / G) % G, xm = rr % G;

        float xs[8];
#pragma unroll
        for (int j = 0; j < 8; ++j) {
            int k = q * 8 + j;
            int kd = k / 9, kh = (k / 3) % 3, kw = k % 3;
            int id = dm + kd - 1, ih = hm + kh - 1, ix = xm + kw - 1;
            bool ok = (k < 27) && ((unsigned)id < (unsigned)G) &&
                      ((unsigned)ih < (unsigned)G) && ((unsigned)ix < (unsigned)G);
            const float* xp = ok ? (x + (((size_t)b * G + id) * G + ih) * G + ix) : zerof;
            xs[j] = *xp;
        }
        ushort_t av[8];
#pragma unroll
        for (int j = 0; j < 8; ++j) av[j] = f2b(xs[j]);
        short8 a = *reinterpret_cast<short8*>(av);
        f32x4 acc = {0.f, 0.f, 0.f, 0.f};
        acc = __builtin_amdgcn_mfma_f32_16x16x32_bf16(a, bfr, acc, 0, 0, 0);

#pragma unroll
        for (int i = 0; i < 4; ++i) {
            int oidx = chunk * 16 + q * 4 + i;
            float xv = acc[i] + bn;
            float s = xv;
#pragma unroll
            for (int mk = 1; mk < 16; mk <<= 1) s += __shfl_xor(s, mk, 64);
            float mean = s * (1.f / 16.f);
            float dd = xv - mean;
            float ss = dd * dd;
#pragma unroll
            for (int mk = 1; mk < 16; mk <<= 1) ss += __shfl_xor(ss, mk, 64);
            float rs = rsqrtf(ss * (1.f / 16.f) + NEPS);
            float xn = dd * rs;
            float o = fmaxf(gn * (1.f - K_ADA * xn) * xn, 0.f);
            if (oidx < nact) {
                int w = list[oidx];
                h1b[(size_t)w * 16 + m] = f2b(o);  // listed voxels are active
            }
        }
    }
}

// ---- layer 2: halo-tile MFMA. Block = 4x4x4 out tile, halo 9^3 x 16ch in LDS ----
__global__ __launch_bounds__(256, 4) void conv2_tile_k(
    const ushort_t* __restrict__ h1b, const ushort_t* __restrict__ wp2,
    const float* __restrict__ bias, const float* __restrict__ gain,
    const float* __restrict__ m2, const ushort_t* __restrict__ zp,
    ushort_t* __restrict__ h2b)
{
    constexpr int GI = 96, G = 48;
    __shared__ __align__(16) ushort_t halo[729 * 3 * 8];  // stride 3 chunks/voxel

    int bid = blockIdx.x;
    int b = bid / 1728;
    int r = bid % 1728;
    int td = r / 144, th = (r / 12) % 12, tx = r % 12;
    int d0 = 4 * td, h0 = 4 * th, x0 = 4 * tx;
    int bd = 2 * d0 - 1, bh = 2 * h0 - 1, bx = 2 * x0 - 1;

    for (int c = threadIdx.x; c < 1458; c += 256) {
        int hv = c >> 1, j = c & 1;
        int gd = bd + hv / 81;
        int gh = bh + (hv / 9) % 9;
        int gx = bx + hv % 9;
        bool ok = ((unsigned)gd < (unsigned)GI) && ((unsigned)gh < (unsigned)GI) &&
                  ((unsigned)gx < (unsigned)GI);
        const ushort_t* p = ok ? (h1b + ((((size_t)b * GI + gd) * GI + gh) * GI + gx) * 16 + j * 8) : zp;
        *reinterpret_cast<short8*>(halo + ((size_t)hv * 3 + j) * 8) =
            *reinterpret_cast<const short8*>(p);
    }
    __syncthreads();

    int wv = threadIdx.x >> 6;   // wave = output d-slice
    int lane = threadIdx.x & 63;
    int m = lane & 15, q = lane >> 4;
    int mh = m >> 2, mx = m & 3;
    int tq = q >> 1, hq = q & 1;
    int hbase = 162 * wv + 18 * mh + 2 * mx;

    f32x4 accs[2];
#pragma unroll
    for (int ct = 0; ct < 2; ++ct) {
        f32x4 acc = {0.f, 0.f, 0.f, 0.f};
#pragma unroll
        for (int g = 0; g < 2; ++g) {
            short8 ab[7], bb[7];
#pragma unroll
            for (int j = 0; j < 7; ++j) {
                const int p = g * 7 + j;
                int hv = hbase + (tq ? tapd2(2 * p + 1) : tapd2(2 * p));
                ab[j] = *reinterpret_cast<const short8*>(halo + ((size_t)hv * 3 + hq) * 8);
                bb[j] = *reinterpret_cast<const short8*>(
                    wp2 + ((size_t)(p * 2 + ct) * 64 + lane) * 8);
            }
#pragma unroll
            for (int j = 0; j < 7; ++j)
                acc = __builtin_amdgcn_mfma_f32_16x16x32_bf16(ab[j], bb[j], acc, 0, 0, 0);
        }
        accs[ct] = acc;
    }

    // fused 32-ch AdaNorm+ReLU (reduce over m-lanes within q-group)
    float b0 = bias[m], b1 = bias[16 + m];
    float g0 = gain[m], g1 = gain[16 + m];
#pragma unroll
    for (int i = 0; i < 4; ++i) {
        int rr2 = q * 4 + i;
        int w = ((b * G + d0 + wv) * G + h0 + (rr2 >> 2)) * G + x0 + (rr2 & 3);
        float xv0 = accs[0][i] + b0;
        float xv1 = accs[1][i] + b1;
        float s = xv0 + xv1;
#pragma unroll
        for (int mk = 1; mk < 16; mk <<= 1) s += __shfl_xor(s, mk, 64);
        float mean = s * (1.f / 32.f);
        float dd0 = xv0 - mean, dd1 = xv1 - mean;
        float ss = dd0 * dd0 + dd1 * dd1;
#pragma unroll
        for (int mk = 1; mk < 16; mk <<= 1) ss += __shfl_xor(ss, mk, 64);
        float rs = rsqrtf(ss * (1.f / 32.f) + NEPS);
        float mv = m2[w];
        float xn0 = dd0 * rs, xn1 = dd1 * rs;
        float o0 = fmaxf(g0 * (1.f - K_ADA * xn0) * xn0, 0.f);
        float o1 = fmaxf(g1 * (1.f - K_ADA * xn1) * xn1, 0.f);
        if (mv == 0.f) { o0 = 0.f; o1 = 0.f; }
        h2b[(size_t)w * 32 + m]      = f2b(o0);
        h2b[(size_t)w * 32 + 16 + m] = f2b(o1);
    }
}

// ---- layer 3: halo-tile MFMA. Block = 4x4x4 out tile, halo 6^3 x 32ch in LDS ----
__global__ __launch_bounds__(256, 4) void conv3_tile_k(
    const ushort_t* __restrict__ h2b, const ushort_t* __restrict__ wp3,
    const float* __restrict__ bias, const float* __restrict__ gain,
    const float* __restrict__ m2, const ushort_t* __restrict__ zp,
    ushort_t* __restrict__ h3b)
{
    constexpr int G = 48;
    __shared__ __align__(16) ushort_t halo[216 * 5 * 8];  // PADC=5 -> 2-way only

    int bid = blockIdx.x;
    int b = bid / 1728;
    int r = bid % 1728;
    int td = r / 144, th = (r / 12) % 12, tx = r % 12;
    int d0 = 4 * td, h0 = 4 * th, x0 = 4 * tx;
    int bd = d0 - 1, bh = h0 - 1, bx = x0 - 1;

    for (int c = threadIdx.x; c < 864; c += 256) {
        int hv = c >> 2, j = c & 3;
        int gd = bd + hv / 36;
        int gh = bh + (hv / 6) % 6;
        int gx = bx + hv % 6;
        bool ok = ((unsigned)gd < (unsigned)G) && ((unsigned)gh < (unsigned)G) &&
                  ((unsigned)gx < (unsigned)G);
        const ushort_t* p = ok ? (h2b + ((((size_t)b * G + gd) * G + gh) * G + gx) * 32 + j * 8) : zp;
        *reinterpret_cast<short8*>(halo + ((size_t)hv * 5 + j) * 8) =
            *reinterpret_cast<const short8*>(p);
    }
    __syncthreads();

    int wv = threadIdx.x >> 6;   // wave = output d-slice
    int lane = threadIdx.x & 63;
    int m = lane & 15, q = lane >> 4;
    int mh = m >> 2, mx = m & 3;
    int hbase = 36 * wv + 6 * mh + mx;

    f32x4 accs[2];
#pragma unroll
    for (int ct = 0; ct < 2; ++ct) {
        f32x4 acc = {0.f, 0.f, 0.f, 0.f};
#pragma unroll
        for (int g = 0; g < 3; ++g) {
            short8 ab[9], bb[9];
#pragma unroll
            for (int j = 0; j < 9; ++j) {
                const int tap = g * 9 + j;
                const int kd = tap / 9, kh = (tap / 3) % 3, kw = tap % 3;
                int hv = hbase + kd * 36 + kh * 6 + kw;
                ab[j] = *reinterpret_cast<const short8*>(halo + ((size_t)hv * 5 + q) * 8);
                bb[j] = *reinterpret_cast<const short8*>(
                    wp3 + ((size_t)(tap * 2 + ct) * 64 + lane) * 8);
            }
#pragma unroll
            for (int j = 0; j < 9; ++j)
                acc = __builtin_amdgcn_mfma_f32_16x16x32_bf16(ab[j], bb[j], acc, 0, 0, 0);
        }
        accs[ct] = acc;
    }

    float b0 = bias[m], b1 = bias[16 + m];
    float g0 = gain[m], g1 = gain[16 + m];
#pragma unroll
    for (int i = 0; i < 4; ++i) {
        int rr2 = q * 4 + i;
        int w = ((b * G + d0 + wv) * G + h0 + (rr2 >> 2)) * G + x0 + (rr2 & 3);
        float xv0 = accs[0][i] + b0;
        float xv1 = accs[1][i] + b1;
        float s = xv0 + xv1;
#pragma unroll
        for (int mk = 1; mk < 16; mk <<= 1) s += __shfl_xor(s, mk, 64);
        float mean = s * (1.f / 32.f);
        float dd0 = xv0 - mean, dd1 = xv1 - mean;
        float ss = dd0 * dd0 + dd1 * dd1;
#pragma unroll
        for (int mk = 1; mk < 16; mk <<= 1) ss += __shfl_xor(ss, mk, 64);
        float rs = rsqrtf(ss * (1.f / 32.f) + NEPS);
        float mv = m2[w];
        float xn0 = dd0 * rs, xn1 = dd1 * rs;
        float o0 = fmaxf(g0 * (1.f - K_ADA * xn0) * xn0, 0.f);
        float o1 = fmaxf(g1 * (1.f - K_ADA * xn1) * xn1, 0.f);
        if (mv == 0.f) { o0 = 0.f; o1 = 0.f; }
        h3b[(size_t)w * 32 + m]      = f2b(o0);
        h3b[(size_t)w * 32 + 16 + m] = f2b(o1);
    }
}

// ---- layers 4/5: HALO-TILE implicit GEMM (unchanged from R8 win) ----
template <int G_IN, int CIN, int STRIDE, bool OUTB>
__global__ __launch_bounds__(256, 4) void conv45_tile_k(
    const ushort_t* __restrict__ Ab, const ushort_t* __restrict__ Wp,
    const float* __restrict__ bias, const float* __restrict__ gain,
    const float* __restrict__ mask,
    ushort_t* __restrict__ outb, float* __restrict__ outf)
{
    constexpr int G = 24;
    constexpr int NKH = CIN / 32;
    constexpr int NCH = CIN / 8;
    constexpr int PADC = NCH + 1;
    constexpr int HD = STRIDE + 3;
    constexpr int HH = STRIDE + 3;
    constexpr int HX = 3 * STRIDE + 3;
    constexpr int NHV = HD * HH * HX;
    constexpr int NCHUNK = NHV * NCH;

    __shared__ __align__(16) ushort_t halo[NHV * PADC * 8];
    __shared__ float nbuf[16][65];

    int bid = blockIdx.x;
    int b = bid / 864;
    int r = bid % 864;
    int td = r / 72, th = (r / 6) % 12, tx = r % 6;
    int d0 = 2 * td, h0 = 2 * th, x0 = 4 * tx;
    int bd = d0 * STRIDE - 1, bh = h0 * STRIDE - 1, bx = x0 * STRIDE - 1;

    for (int c = threadIdx.x; c < NCHUNK; c += 256) {
        int hv = c / NCH, j = c % NCH;
        int gd = bd + hv / (HH * HX);
        int gh = bh + (hv / HX) % HH;
        int gx = bx + hv % HX;
        short8 val = {0, 0, 0, 0, 0, 0, 0, 0};
        if ((unsigned)gd < (unsigned)G_IN && (unsigned)gh < (unsigned)G_IN &&
            (unsigned)gx < (unsigned)G_IN)
            val = *reinterpret_cast<const short8*>(
                Ab + ((((size_t)b * G_IN + gd) * G_IN + gh) * G_IN + gx) * CIN + j * 8);
        *reinterpret_cast<short8*>(halo + ((size_t)hv * PADC + j) * 8) = val;
    }
    __syncthreads();

    int ct = threadIdx.x >> 6;
    int lane = threadIdx.x & 63;
    int m = lane & 15, q = lane >> 4;
    int md = (m >> 3) & 1, mh = (m >> 2) & 1, mx = m & 3;

    f32x4 acc = {0.f, 0.f, 0.f, 0.f};
    constexpr int NT = 27 * NKH;
    constexpr int GSZ = 9;
#pragma unroll
    for (int g = 0; g < NT / GSZ; ++g) {
        short8 ab[GSZ], bb[GSZ];
#pragma unroll
        for (int j = 0; j < GSZ; ++j) {
            int it = g * GSZ + j;
            int tap = it / NKH, k2 = it % NKH;
            const int kd = tap / 9, kh = (tap / 3) % 3, kw = tap % 3;
            int hv = ((md * STRIDE + kd) * HH + (mh * STRIDE + kh)) * HX +
                     (mx * STRIDE + kw);
            ab[j] = *reinterpret_cast<const short8*>(
                halo + ((size_t)hv * PADC + k2 * 4 + q) * 8);
            bb[j] = *reinterpret_cast<const short8*>(
                Wp + (((size_t)(tap * 4 + ct) * NKH + k2) * 64 + lane) * 8);
        }
#pragma unroll
        for (int j = 0; j < GSZ; ++j)
            acc = __builtin_amdgcn_mfma_f32_16x16x32_bf16(ab[j], bb[j], acc, 0, 0, 0);
    }

    float bn = bias[ct * 16 + m];
#pragma unroll
    for (int i = 0; i < 4; ++i) nbuf[q * 4 + i][ct * 16 + m] = acc[i] + bn;
    __syncthreads();

    float gn = gain[lane];
#pragma unroll
    for (int i = 0; i < 4; ++i) {
        int vloc = ct * 4 + i;
        int vd = d0 + ((vloc >> 3) & 1);
        int vh = h0 + ((vloc >> 2) & 1);
        int vx = x0 + (vloc & 3);
        int w = ((b * G + vd) * G + vh) * G + vx;
        float val = nbuf[vloc][lane];
        float mean = wave_sum64(val) * (1.f / 64.f);
        float dd = val - mean;
        float var = wave_sum64(dd * dd) * (1.f / 64.f) + NEPS;
        float xn = dd * rsqrtf(var);
        float o = fmaxf(gn * (1.f - K_ADA * xn) * xn, 0.f);
        if (mask[w] == 0.f) o = 0.f;
        if (OUTB) outb[(size_t)w * 64 + lane] = f2b(o);
        else      outf[(size_t)w * 64 + lane] = o;
    }
}

// ---- Global max pool stage 1 ----
__global__ __launch_bounds__(256) void pool1_k(const float* __restrict__ h5,
                                               float* __restrict__ partials)
{
    int chunk = blockIdx.x % 54;
    int b = blockIdx.x / 54;
    int c = threadIdx.x & 63;
    int s = threadIdx.x >> 6;
    const float* base = h5 + ((size_t)b * 13824 + chunk * 256) * 64;
    float mx = 0.f;
#pragma unroll 4
    for (int v = s; v < 256; v += 4) mx = fmaxf(mx, base[v * 64 + c]);
    __shared__ float red[256];
    red[threadIdx.x] = mx;
    __syncthreads();
    if (s == 0)
        partials[blockIdx.x * 64 + c] =
            fmaxf(fmaxf(red[c], red[64 + c]), fmaxf(red[128 + c], red[192 + c]));
}

// ---- stage 2 + head ----
__global__ __launch_bounds__(128) void pool2_head_k(const float* __restrict__ partials,
                                                    const float* __restrict__ wh,
                                                    const float* __restrict__ bh,
                                                    const float* __restrict__ gh,
                                                    float* __restrict__ out)
{
    __shared__ float pooled[2][64];
    int t = threadIdx.x;
    int b = t >> 6;
    int f = t & 63;
    float mx = 0.f;
    for (int p = 0; p < 54; ++p) mx = fmaxf(mx, partials[(b * 54 + p) * 64 + f]);
    pooled[b][f] = mx;
    __syncthreads();
    float acc = bh[f];
#pragma unroll
    for (int k = 0; k < 64; ++k) acc += pooled[b][k] * wh[k * 64 + f];
    float mean = wave_sum64(acc) * (1.f / 64.f);
    float dd = acc - mean;
    float var = wave_sum64(dd * dd) * (1.f / 64.f) + NEPS;
    float xn = dd * rsqrtf(var);
    float val = gh[f] * (1.f - K_ADA * xn) * xn;
    out[t] = fmaxf(val, 0.f);
}

extern "C" void kernel_launch(void* const* d_in, const int* in_sizes, int n_in,
                              void* d_out, int out_size, void* d_ws, size_t ws_size,
                              hipStream_t stream)
{
    const float* x  = (const float*)d_in[0];
    const float* m1 = (const float*)d_in[1];
    const float* w1 = (const float*)d_in[2];
    const float* b1 = (const float*)d_in[3];
    const float* g1 = (const float*)d_in[4];
    const float* w2 = (const float*)d_in[5];
    const float* b2 = (const float*)d_in[6];
    const float* g2 = (const float*)d_in[7];
    const float* w3 = (const float*)d_in[8];
    const float* b3 = (const float*)d_in[9];
    const float* g3 = (const float*)d_in[10];
    const float* w4 = (const float*)d_in[11];
    const float* b4 = (const float*)d_in[12];
    const float* g4 = (const float*)d_in[13];
    const float* w5 = (const float*)d_in[14];
    const float* b5 = (const float*)d_in[15];
    const float* g5 = (const float*)d_in[16];
    const float* wh = (const float*)d_in[17];
    const float* bh = (const float*)d_in[18];
    const float* gh = (const float*)d_in[19];
    float* out = (float*)d_out;

    // workspace layout (float units; all 16B aligned)
    float* ws = (float*)d_ws;
    ushort_t* h1b = (ushort_t*)ws;                 // 28,311,552 u = 14,155,776 f
    ushort_t* h2b = (ushort_t*)(ws + 14155776);    //  7,077,888 u =  3,538,944 f
    ushort_t* h3b = (ushort_t*)(ws + 17694720);    //  7,077,888 u =  3,538,944 f
    ushort_t* h4b = (ushort_t*)(ws + 21233664);    //  1,769,472 u =    884,736 f
    float* h5 = ws + 22118400;                     //  1,769,472 f
    float* m2 = ws + 23887872;                     //    221,184 f
    float* m3 = ws + 24109056;                     //     27,648 f
    float* partials = ws + 24136704;               //      6,912 f
    ushort_t* wp1 = (ushort_t*)(ws + 24143616);    //     512 u =    256 f
    ushort_t* wp2 = (ushort_t*)(ws + 24143872);    //  14,336 u =  7,168 f
    ushort_t* wp3 = (ushort_t*)(ws + 24151040);    //  27,648 u = 13,824 f
    ushort_t* wp4 = (ushort_t*)(ws + 24164864);    //  55,296 u = 27,648 f
    ushort_t* wp5 = (ushort_t*)(ws + 24192512);    // 110,592 u = 55,296 f
    float* zeropad = ws + 24247808;                //          8 f (32B zero block)
    int* counter = (int*)(ws + 24247816);          //          1 int
    // active-voxel list ALIASES h2b region (list consumed before conv2 writes h2b)
    int* list = (int*)(ws + 14155776);

    prep_k<<<1679, 256, 0, stream>>>(w1, w2, w3, w4, w5, m1,
                                     wp1, wp2, wp3, wp4, wp5, m2, zeropad, counter);
    dmask_k<24, 48><<<108, 256, 0, stream>>>(m2, m3);

    const ushort_t* zp = (const ushort_t*)zeropad;
    // layer 1: zero-fill + compact, then active-only MFMA
    conv1_fill_k<<<6912, 256, 0, stream>>>(m1, h1b, list, counter);
    conv1_act_k<<<864, 256, 0, stream>>>(x, list, counter, wp1, b1, g1, zeropad, h1b);
    // layer 2: halo-tile LDS MFMA + fused norm
    conv2_tile_k<<<3456, 256, 0, stream>>>(h1b, wp2, b2, g2, m2, zp, h2b);
    // layer 3: halo-tile LDS MFMA + fused norm
    conv3_tile_k<<<3456, 256, 0, stream>>>(h2b, wp3, b3, g3, m2, zp, h3b);
    // layer 4/5: halo-tile LDS MFMA + fused 64-ch norm
    conv45_tile_k<48, 32, 2, true><<<1728, 256, 0, stream>>>(h3b, wp4, b4, g4, m3, h4b, nullptr);
    conv45_tile_k<24, 64, 1, false><<<1728, 256, 0, stream>>>(h4b, wp5, b5, g5, m3, nullptr, h5);

    // pool + head
    pool1_k<<<108, 256, 0, stream>>>(h5, partials);
    pool2_head_k<<<1, 128, 0, stream>>>(partials, wh, bh, gh, out);
}

// Round 10
// 244.094 us; speedup vs baseline: 2.2180x; 2.2180x over previous
//
#include <hip/hip_runtime.h>
#include <math.h>

#define K_ADA 0.1f
#define NEPS 1e-5f

typedef __attribute__((ext_vector_type(8))) short short8;
typedef __attribute__((ext_vector_type(4))) float f32x4;
typedef unsigned short ushort_t;

__device__ __forceinline__ ushort_t f2b(float f) {
    union { float f; unsigned u; } v; v.f = f;
    unsigned r = (v.u + 0x7fffu + ((v.u >> 16) & 1u)) >> 16;
    return (ushort_t)r;
}

__device__ __forceinline__ float wave_sum64(float v) {
#pragma unroll
    for (int m = 1; m < 64; m <<= 1) v += __shfl_xor(v, m, 64);
    return v;
}

// tap -> halo delta (stride-2 input, 9x9 plane): kd*81 + kh*9 + kw; tap 27 pads to 0
__host__ __device__ constexpr int tapd2(int tap) {
    return tap >= 27 ? 0 : (tap / 9) * 81 + ((tap / 3) % 3) * 9 + (tap % 3);
}

// ---- generic pack element: [3,3,3,CIN,COUT] fp32 -> B-fragment bf16 ----
template <int CIN, int COUT>
__device__ __forceinline__ void pack_w_el(const float* __restrict__ w,
                                          ushort_t* __restrict__ wp, int t)
{
    constexpr int NKH = CIN / 32;
    constexpr int NCT = COUT / 16;
    int jj = t & 7;
    int lane = (t >> 3) & 63;
    int rest = t >> 9;              // (tap*NCT + ct)*NKH + kh
    int kh = rest % NKH;
    int rest2 = rest / NKH;
    int ct = rest2 % NCT;
    int tap = rest2 / NCT;
    int cin = kh * 32 + (lane >> 4) * 8 + jj;
    int cout = ct * 16 + (lane & 15);
    wp[t] = f2b(w[(tap * CIN + cin) * COUT + cout]);
}

// ---- merged prep: pack w1..w5 + dmask m1->m2 + zero-pad + 64 counters ----
__global__ __launch_bounds__(256) void prep_k(
    const float* __restrict__ w1, const float* __restrict__ w2,
    const float* __restrict__ w3, const float* __restrict__ w4,
    const float* __restrict__ w5, const float* __restrict__ m1,
    ushort_t* __restrict__ wp1, ushort_t* __restrict__ wp2,
    ushort_t* __restrict__ wp3, ushort_t* __restrict__ wp4,
    ushort_t* __restrict__ wp5, float* __restrict__ m2,
    float* __restrict__ zeropad, int* __restrict__ counters)
{
    int t = blockIdx.x * 256 + threadIdx.x;
    if (t < 512) {
        // w1 [27][1][16] -> single frag, K=taps (pad 32)
        int jj = t & 7;
        int lane = t >> 3;
        int tap = (lane >> 4) * 8 + jj;
        int cout = lane & 15;
        wp1[t] = (tap < 27) ? f2b(w1[tap * 16 + cout]) : (ushort_t)0;
    } else if (t < 14848) {
        // w2 [27][16][32] -> tap-paired frags: 14 pairs x 2 ct
        int u = t - 512;
        int jj = u & 7;
        int lane = (u >> 3) & 63;
        int rest = u >> 9;
        int ct = rest & 1;
        int p = rest >> 1;
        int tap = 2 * p + (lane >> 5);
        int cin = ((lane >> 4) & 1) * 8 + jj;
        int cout = ct * 16 + (lane & 15);
        wp2[u] = (tap < 27) ? f2b(w2[(tap * 16 + cin) * 32 + cout]) : (ushort_t)0;
    } else if (t < 42496) {
        pack_w_el<32, 32>(w3, wp3, t - 14848);
    } else if (t < 97792) {
        pack_w_el<32, 64>(w4, wp4, t - 42496);
    } else if (t < 208384) {
        pack_w_el<64, 64>(w5, wp5, t - 97792);
    } else if (t < 429568) {
        // dmask 96 -> 48
        int v = t - 208384;
        constexpr int GO = 48, GI = 96;
        int b = v / (GO * GO * GO);
        int r = v % (GO * GO * GO);
        int d = r / (GO * GO), h = (r / GO) % GO, x = r % GO;
        float mx = 0.f;
        for (int kd = 0; kd < 3; ++kd) {
            int zd = 2 * d + kd - 1; if ((unsigned)zd >= GI) continue;
            for (int kh = 0; kh < 3; ++kh) {
                int zh = 2 * h + kh - 1; if ((unsigned)zh >= GI) continue;
                for (int kw = 0; kw < 3; ++kw) {
                    int zx = 2 * x + kw - 1; if ((unsigned)zx >= GI) continue;
                    mx = fmaxf(mx, m1[((b * GI + zd) * GI + zh) * GI + zx]);
                }
            }
        }
        m2[v] = mx;
    } else if (t < 429576) {
        zeropad[t - 429568] = 0.f;  // 32B zero block for OOB load redirection
    } else if (t < 431624) {
        counters[t - 429576] = 0;   // 64 counters, 128B-spaced (2048 ints)
    }
}

// downsample mask: max over 3^3 window, stride 2, pad 1 (m2 -> m3)
template <int GO, int GI>
__global__ __launch_bounds__(256) void dmask_k(const float* __restrict__ mi,
                                               float* __restrict__ mo)
{
    constexpr int N = 2 * GO * GO * GO;
    int v = blockIdx.x * 256 + threadIdx.x;
    if (v >= N) return;
    int b = v / (GO * GO * GO);
    int r = v % (GO * GO * GO);
    int d = r / (GO * GO), h = (r / GO) % GO, x = r % GO;
    float mx = 0.f;
    for (int kd = 0; kd < 3; ++kd) {
        int zd = 2 * d + kd - 1; if ((unsigned)zd >= GI) continue;
        for (int kh = 0; kh < 3; ++kh) {
            int zh = 2 * h + kh - 1; if ((unsigned)zh >= GI) continue;
            for (int kw = 0; kw < 3; ++kw) {
                int zx = 2 * x + kw - 1; if ((unsigned)zx >= GI) continue;
                mx = fmaxf(mx, mi[((b * GI + zd) * GI + zh) * GI + zx]);
            }
        }
    }
    mo[v] = mx;
}

// ---- conv1 stage A: zero-fill h1b + compact actives into 64 partitions ----
// Wave w scatters via counters[w&63] (128B-spaced -> parallel L2 slices; no
// same-line serialization — R9's single counter cost 27 cyc/atomic x 27648).
__global__ __launch_bounds__(256) void conv1_fill_k(const float* __restrict__ m1,
                                                    ushort_t* __restrict__ h1b,
                                                    int* __restrict__ list,
                                                    int* __restrict__ counters)
{
    int v = blockIdx.x * 256 + threadIdx.x;  // grid covers exactly 2*96^3
    const short8 z = {0, 0, 0, 0, 0, 0, 0, 0};
    short8* hp = reinterpret_cast<short8*>(h1b + (size_t)v * 16);
    hp[0] = z; hp[1] = z;
    bool act = (m1[v] != 0.f);
    unsigned long long msk = __ballot(act);
    int lane = threadIdx.x & 63;
    int gwave = v >> 6;
    int p = gwave & 63;
    int base = 0;
    int cnt = __popcll(msk);
    if (lane == 0 && cnt) base = atomicAdd(&counters[p * 32], cnt);
    base = __shfl(base, 0, 64);
    if (act) {
        int pre = __popcll(msk & ((1ull << lane) - 1ull));
        list[p * 27648 + base + pre] = v;
    }
}

// ---- conv1 stage B: MFMA over ACTIVE voxels only; 64 partitions, 54 waves each ----
__global__ __launch_bounds__(256) void conv1_act_k(const float* __restrict__ x,
                                                   const int* __restrict__ list,
                                                   const int* __restrict__ counters,
                                                   const ushort_t* __restrict__ wp1,
                                                   const float* __restrict__ bias,
                                                   const float* __restrict__ gain,
                                                   const float* __restrict__ zerof,
                                                   ushort_t* __restrict__ h1b)
{
    constexpr int G = 96, G3 = G * G * G;
    int gwave = (blockIdx.x * 256 + threadIdx.x) >> 6;  // 0..3455
    int p = gwave & 63;
    int lw = gwave >> 6;                                 // 0..53
    int nact = counters[p * 32];
    if (nact <= 0) return;
    const int* plist = list + p * 27648;
    int lane = threadIdx.x & 63;
    int m = lane & 15, q = lane >> 4;
    int nchunk = (nact + 15) >> 4;
    float bn = bias[m], gn = gain[m];
    short8 bfr = *reinterpret_cast<const short8*>(wp1 + lane * 8);

    for (int chunk = lw; chunk < nchunk; chunk += 54) {
        int idx = chunk * 16 + m;
        int vm = plist[min(idx, nact - 1)];
        int b = vm / G3;
        int rr = vm % G3;
        int dm = rr / (G * G), hm = (rr / G) % G, xm = rr % G;

        float xs[8];
#pragma unroll
        for (int j = 0; j < 8; ++j) {
            int k = q * 8 + j;
            int kd = k / 9, kh = (k / 3) % 3, kw = k % 3;
            int id = dm + kd - 1, ih = hm + kh - 1, ix = xm + kw - 1;
            bool ok = (k < 27) && ((unsigned)id < (unsigned)G) &&
                      ((unsigned)ih < (unsigned)G) && ((unsigned)ix < (unsigned)G);
            const float* xp = ok ? (x + (((size_t)b * G + id) * G + ih) * G + ix) : zerof;
            xs[j] = *xp;
        }
        ushort_t av[8];
#pragma unroll
        for (int j = 0; j < 8; ++j) av[j] = f2b(xs[j]);
        short8 a = *reinterpret_cast<short8*>(av);
        f32x4 acc = {0.f, 0.f, 0.f, 0.f};
        acc = __builtin_amdgcn_mfma_f32_16x16x32_bf16(a, bfr, acc, 0, 0, 0);

#pragma unroll
        for (int i = 0; i < 4; ++i) {
            int oidx = chunk * 16 + q * 4 + i;
            float xv = acc[i] + bn;
            float s = xv;
#pragma unroll
            for (int mk = 1; mk < 16; mk <<= 1) s += __shfl_xor(s, mk, 64);
            float mean = s * (1.f / 16.f);
            float dd = xv - mean;
            float ss = dd * dd;
#pragma unroll
            for (int mk = 1; mk < 16; mk <<= 1) ss += __shfl_xor(ss, mk, 64);
            float rs = rsqrtf(ss * (1.f / 16.f) + NEPS);
            float xn = dd * rs;
            float o = fmaxf(gn * (1.f - K_ADA * xn) * xn, 0.f);
            if (oidx < nact) {
                int w = plist[oidx];
                h1b[(size_t)w * 16 + m] = f2b(o);  // listed voxels are active
            }
        }
    }
}

// ---- layer 2: halo-tile MFMA. Block = 4x4x4 out tile, halo 9^3 x 16ch in LDS ----
__global__ __launch_bounds__(256, 4) void conv2_tile_k(
    const ushort_t* __restrict__ h1b, const ushort_t* __restrict__ wp2,
    const float* __restrict__ bias, const float* __restrict__ gain,
    const float* __restrict__ m2, const ushort_t* __restrict__ zp,
    ushort_t* __restrict__ h2b)
{
    constexpr int GI = 96, G = 48;
    __shared__ __align__(16) ushort_t halo[729 * 3 * 8];  // stride 3 chunks/voxel

    int bid = blockIdx.x;
    int b = bid / 1728;
    int r = bid % 1728;
    int td = r / 144, th = (r / 12) % 12, tx = r % 12;
    int d0 = 4 * td, h0 = 4 * th, x0 = 4 * tx;
    int bd = 2 * d0 - 1, bh = 2 * h0 - 1, bx = 2 * x0 - 1;

    for (int c = threadIdx.x; c < 1458; c += 256) {
        int hv = c >> 1, j = c & 1;
        int gd = bd + hv / 81;
        int gh = bh + (hv / 9) % 9;
        int gx = bx + hv % 9;
        bool ok = ((unsigned)gd < (unsigned)GI) && ((unsigned)gh < (unsigned)GI) &&
                  ((unsigned)gx < (unsigned)GI);
        const ushort_t* p = ok ? (h1b + ((((size_t)b * GI + gd) * GI + gh) * GI + gx) * 16 + j * 8) : zp;
        *reinterpret_cast<short8*>(halo + ((size_t)hv * 3 + j) * 8) =
            *reinterpret_cast<const short8*>(p);
    }
    __syncthreads();

    int wv = threadIdx.x >> 6;   // wave = output d-slice
    int lane = threadIdx.x & 63;
    int m = lane & 15, q = lane >> 4;
    int mh = m >> 2, mx = m & 3;
    int tq = q >> 1, hq = q & 1;
    int hbase = 162 * wv + 18 * mh + 2 * mx;

    f32x4 accs[2];
#pragma unroll
    for (int ct = 0; ct < 2; ++ct) {
        f32x4 acc = {0.f, 0.f, 0.f, 0.f};
#pragma unroll
        for (int g = 0; g < 2; ++g) {
            short8 ab[7], bb[7];
#pragma unroll
            for (int j = 0; j < 7; ++j) {
                const int p = g * 7 + j;
                int hv = hbase + (tq ? tapd2(2 * p + 1) : tapd2(2 * p));
                ab[j] = *reinterpret_cast<const short8*>(halo + ((size_t)hv * 3 + hq) * 8);
                bb[j] = *reinterpret_cast<const short8*>(
                    wp2 + ((size_t)(p * 2 + ct) * 64 + lane) * 8);
            }
#pragma unroll
            for (int j = 0; j < 7; ++j)
                acc = __builtin_amdgcn_mfma_f32_16x16x32_bf16(ab[j], bb[j], acc, 0, 0, 0);
        }
        accs[ct] = acc;
    }

    // fused 32-ch AdaNorm+ReLU (reduce over m-lanes within q-group)
    float b0 = bias[m], b1 = bias[16 + m];
    float g0 = gain[m], g1 = gain[16 + m];
#pragma unroll
    for (int i = 0; i < 4; ++i) {
        int rr2 = q * 4 + i;
        int w = ((b * G + d0 + wv) * G + h0 + (rr2 >> 2)) * G + x0 + (rr2 & 3);
        float xv0 = accs[0][i] + b0;
        float xv1 = accs[1][i] + b1;
        float s = xv0 + xv1;
#pragma unroll
        for (int mk = 1; mk < 16; mk <<= 1) s += __shfl_xor(s, mk, 64);
        float mean = s * (1.f / 32.f);
        float dd0 = xv0 - mean, dd1 = xv1 - mean;
        float ss = dd0 * dd0 + dd1 * dd1;
#pragma unroll
        for (int mk = 1; mk < 16; mk <<= 1) ss += __shfl_xor(ss, mk, 64);
        float rs = rsqrtf(ss * (1.f / 32.f) + NEPS);
        float mv = m2[w];
        float xn0 = dd0 * rs, xn1 = dd1 * rs;
        float o0 = fmaxf(g0 * (1.f - K_ADA * xn0) * xn0, 0.f);
        float o1 = fmaxf(g1 * (1.f - K_ADA * xn1) * xn1, 0.f);
        if (mv == 0.f) { o0 = 0.f; o1 = 0.f; }
        h2b[(size_t)w * 32 + m]      = f2b(o0);
        h2b[(size_t)w * 32 + 16 + m] = f2b(o1);
    }
}

// ---- layer 3: halo-tile MFMA. Block = 4x4x4 out tile, halo 6^3 x 32ch in LDS ----
__global__ __launch_bounds__(256, 4) void conv3_tile_k(
    const ushort_t* __restrict__ h2b, const ushort_t* __restrict__ wp3,
    const float* __restrict__ bias, const float* __restrict__ gain,
    const float* __restrict__ m2, const ushort_t* __restrict__ zp,
    ushort_t* __restrict__ h3b)
{
    constexpr int G = 48;
    __shared__ __align__(16) ushort_t halo[216 * 5 * 8];  // PADC=5 -> 2-way only

    int bid = blockIdx.x;
    int b = bid / 1728;
    int r = bid % 1728;
    int td = r / 144, th = (r / 12) % 12, tx = r % 12;
    int d0 = 4 * td, h0 = 4 * th, x0 = 4 * tx;
    int bd = d0 - 1, bh = h0 - 1, bx = x0 - 1;

    for (int c = threadIdx.x; c < 864; c += 256) {
        int hv = c >> 2, j = c & 3;
        int gd = bd + hv / 36;
        int gh = bh + (hv / 6) % 6;
        int gx = bx + hv % 6;
        bool ok = ((unsigned)gd < (unsigned)G) && ((unsigned)gh < (unsigned)G) &&
                  ((unsigned)gx < (unsigned)G);
        const ushort_t* p = ok ? (h2b + ((((size_t)b * G + gd) * G + gh) * G + gx) * 32 + j * 8) : zp;
        *reinterpret_cast<short8*>(halo + ((size_t)hv * 5 + j) * 8) =
            *reinterpret_cast<const short8*>(p);
    }
    __syncthreads();

    int wv = threadIdx.x >> 6;   // wave = output d-slice
    int lane = threadIdx.x & 63;
    int m = lane & 15, q = lane >> 4;
    int mh = m >> 2, mx = m & 3;
    int hbase = 36 * wv + 6 * mh + mx;

    f32x4 accs[2];
#pragma unroll
    for (int ct = 0; ct < 2; ++ct) {
        f32x4 acc = {0.f, 0.f, 0.f, 0.f};
#pragma unroll
        for (int g = 0; g < 3; ++g) {
            short8 ab[9], bb[9];
#pragma unroll
            for (int j = 0; j < 9; ++j) {
                const int tap = g * 9 + j;
                const int kd = tap / 9, kh = (tap / 3) % 3, kw = tap % 3;
                int hv = hbase + kd * 36 + kh * 6 + kw;
                ab[j] = *reinterpret_cast<const short8*>(halo + ((size_t)hv * 5 + q) * 8);
                bb[j] = *reinterpret_cast<const short8*>(
                    wp3 + ((size_t)(tap * 2 + ct) * 64 + lane) * 8);
            }
#pragma unroll
            for (int j = 0; j < 9; ++j)
                acc = __builtin_amdgcn_mfma_f32_16x16x32_bf16(ab[j], bb[j], acc, 0, 0, 0);
        }
        accs[ct] = acc;
    }

    float b0 = bias[m], b1 = bias[16 + m];
    float g0 = gain[m], g1 = gain[16 + m];
#pragma unroll
    for (int i = 0; i < 4; ++i) {
        int rr2 = q * 4 + i;
        int w = ((b * G + d0 + wv) * G + h0 + (rr2 >> 2)) * G + x0 + (rr2 & 3);
        float xv0 = accs[0][i] + b0;
        float xv1 = accs[1][i] + b1;
        float s = xv0 + xv1;
#pragma unroll
        for (int mk = 1; mk < 16; mk <<= 1) s += __shfl_xor(s, mk, 64);
        float mean = s * (1.f / 32.f);
        float dd0 = xv0 - mean, dd1 = xv1 - mean;
        float ss = dd0 * dd0 + dd1 * dd1;
#pragma unroll
        for (int mk = 1; mk < 16; mk <<= 1) ss += __shfl_xor(ss, mk, 64);
        float rs = rsqrtf(ss * (1.f / 32.f) + NEPS);
        float mv = m2[w];
        float xn0 = dd0 * rs, xn1 = dd1 * rs;
        float o0 = fmaxf(g0 * (1.f - K_ADA * xn0) * xn0, 0.f);
        float o1 = fmaxf(g1 * (1.f - K_ADA * xn1) * xn1, 0.f);
        if (mv == 0.f) { o0 = 0.f; o1 = 0.f; }
        h3b[(size_t)w * 32 + m]      = f2b(o0);
        h3b[(size_t)w * 32 + 16 + m] = f2b(o1);
    }
}

// ---- layers 4/5: HALO-TILE implicit GEMM ----
template <int G_IN, int CIN, int STRIDE, bool OUTB>
__global__ __launch_bounds__(256, 4) void conv45_tile_k(
    const ushort_t* __restrict__ Ab, const ushort_t* __restrict__ Wp,
    const float* __restrict__ bias, const float* __restrict__ gain,
    const float* __restrict__ mask,
    ushort_t* __restrict__ outb, float* __restrict__ outf)
{
    constexpr int G = 24;
    constexpr int NKH = CIN / 32;
    constexpr int NCH = CIN / 8;
    constexpr int PADC = NCH + 1;
    constexpr int HD = STRIDE + 3;
    constexpr int HH = STRIDE + 3;
    constexpr int HX = 3 * STRIDE + 3;
    constexpr int NHV = HD * HH * HX;
    constexpr int NCHUNK = NHV * NCH;

    __shared__ __align__(16) ushort_t halo[NHV * PADC * 8];
    __shared__ float nbuf[16][65];

    int bid = blockIdx.x;
    int b = bid / 864;
    int r = bid % 864;
    int td = r / 72, th = (r / 6) % 12, tx = r % 6;
    int d0 = 2 * td, h0 = 2 * th, x0 = 4 * tx;
    int bd = d0 * STRIDE - 1, bh = h0 * STRIDE - 1, bx = x0 * STRIDE - 1;

    for (int c = threadIdx.x; c < NCHUNK; c += 256) {
        int hv = c / NCH, j = c % NCH;
        int gd = bd + hv / (HH * HX);
        int gh = bh + (hv / HX) % HH;
        int gx = bx + hv % HX;
        short8 val = {0, 0, 0, 0, 0, 0, 0, 0};
        if ((unsigned)gd < (unsigned)G_IN && (unsigned)gh < (unsigned)G_IN &&
            (unsigned)gx < (unsigned)G_IN)
            val = *reinterpret_cast<const short8*>(
                Ab + ((((size_t)b * G_IN + gd) * G_IN + gh) * G_IN + gx) * CIN + j * 8);
        *reinterpret_cast<short8*>(halo + ((size_t)hv * PADC + j) * 8) = val;
    }
    __syncthreads();

    int ct = threadIdx.x >> 6;
    int lane = threadIdx.x & 63;
    int m = lane & 15, q = lane >> 4;
    int md = (m >> 3) & 1, mh = (m >> 2) & 1, mx = m & 3;

    f32x4 acc = {0.f, 0.f, 0.f, 0.f};
    constexpr int NT = 27 * NKH;
    constexpr int GSZ = 9;
#pragma unroll
    for (int g = 0; g < NT / GSZ; ++g) {
        short8 ab[GSZ], bb[GSZ];
#pragma unroll
        for (int j = 0; j < GSZ; ++j) {
            int it = g * GSZ + j;
            int tap = it / NKH, k2 = it % NKH;
            const int kd = tap / 9, kh = (tap / 3) % 3, kw = tap % 3;
            int hv = ((md * STRIDE + kd) * HH + (mh * STRIDE + kh)) * HX +
                     (mx * STRIDE + kw);
            ab[j] = *reinterpret_cast<const short8*>(
                halo + ((size_t)hv * PADC + k2 * 4 + q) * 8);
            bb[j] = *reinterpret_cast<const short8*>(
                Wp + (((size_t)(tap * 4 + ct) * NKH + k2) * 64 + lane) * 8);
        }
#pragma unroll
        for (int j = 0; j < GSZ; ++j)
            acc = __builtin_amdgcn_mfma_f32_16x16x32_bf16(ab[j], bb[j], acc, 0, 0, 0);
    }

    float bn = bias[ct * 16 + m];
#pragma unroll
    for (int i = 0; i < 4; ++i) nbuf[q * 4 + i][ct * 16 + m] = acc[i] + bn;
    __syncthreads();

    float gn = gain[lane];
#pragma unroll
    for (int i = 0; i < 4; ++i) {
        int vloc = ct * 4 + i;
        int vd = d0 + ((vloc >> 3) & 1);
        int vh = h0 + ((vloc >> 2) & 1);
        int vx = x0 + (vloc & 3);
        int w = ((b * G + vd) * G + vh) * G + vx;
        float val = nbuf[vloc][lane];
        float mean = wave_sum64(val) * (1.f / 64.f);
        float dd = val - mean;
        float var = wave_sum64(dd * dd) * (1.f / 64.f) + NEPS;
        float xn = dd * rsqrtf(var);
        float o = fmaxf(gn * (1.f - K_ADA * xn) * xn, 0.f);
        if (mask[w] == 0.f) o = 0.f;
        if (OUTB) outb[(size_t)w * 64 + lane] = f2b(o);
        else      outf[(size_t)w * 64 + lane] = o;
    }
}

// ---- Global max pool stage 1 ----
__global__ __launch_bounds__(256) void pool1_k(const float* __restrict__ h5,
                                               float* __restrict__ partials)
{
    int chunk = blockIdx.x % 54;
    int b = blockIdx.x / 54;
    int c = threadIdx.x & 63;
    int s = threadIdx.x >> 6;
    const float* base = h5 + ((size_t)b * 13824 + chunk * 256) * 64;
    float mx = 0.f;
#pragma unroll 4
    for (int v = s; v < 256; v += 4) mx = fmaxf(mx, base[v * 64 + c]);
    __shared__ float red[256];
    red[threadIdx.x] = mx;
    __syncthreads();
    if (s == 0)
        partials[blockIdx.x * 64 + c] =
            fmaxf(fmaxf(red[c], red[64 + c]), fmaxf(red[128 + c], red[192 + c]));
}

// ---- stage 2 + head ----
__global__ __launch_bounds__(128) void pool2_head_k(const float* __restrict__ partials,
                                                    const float* __restrict__ wh,
                                                    const float* __restrict__ bh,
                                                    const float* __restrict__ gh,
                                                    float* __restrict__ out)
{
    __shared__ float pooled[2][64];
    int t = threadIdx.x;
    int b = t >> 6;
    int f = t & 63;
    float mx = 0.f;
    for (int p = 0; p < 54; ++p) mx = fmaxf(mx, partials[(b * 54 + p) * 64 + f]);
    pooled[b][f] = mx;
    __syncthreads();
    float acc = bh[f];
#pragma unroll
    for (int k = 0; k < 64; ++k) acc += pooled[b][k] * wh[k * 64 + f];
    float mean = wave_sum64(acc) * (1.f / 64.f);
    float dd = acc - mean;
    float var = wave_sum64(dd * dd) * (1.f / 64.f) + NEPS;
    float xn = dd * rsqrtf(var);
    float val = gh[f] * (1.f - K_ADA * xn) * xn;
    out[t] = fmaxf(val, 0.f);
}

extern "C" void kernel_launch(void* const* d_in, const int* in_sizes, int n_in,
                              void* d_out, int out_size, void* d_ws, size_t ws_size,
                              hipStream_t stream)
{
    const float* x  = (const float*)d_in[0];
    const float* m1 = (const float*)d_in[1];
    const float* w1 = (const float*)d_in[2];
    const float* b1 = (const float*)d_in[3];
    const float* g1 = (const float*)d_in[4];
    const float* w2 = (const float*)d_in[5];
    const float* b2 = (const float*)d_in[6];
    const float* g2 = (const float*)d_in[7];
    const float* w3 = (const float*)d_in[8];
    const float* b3 = (const float*)d_in[9];
    const float* g3 = (const float*)d_in[10];
    const float* w4 = (const float*)d_in[11];
    const float* b4 = (const float*)d_in[12];
    const float* g4 = (const float*)d_in[13];
    const float* w5 = (const float*)d_in[14];
    const float* b5 = (const float*)d_in[15];
    const float* g5 = (const float*)d_in[16];
    const float* wh = (const float*)d_in[17];
    const float* bh = (const float*)d_in[18];
    const float* gh = (const float*)d_in[19];
    float* out = (float*)d_out;

    // workspace layout (float units; all 16B aligned)
    float* ws = (float*)d_ws;
    ushort_t* h1b = (ushort_t*)ws;                 // 28,311,552 u = 14,155,776 f
    ushort_t* h2b = (ushort_t*)(ws + 14155776);    //  7,077,888 u =  3,538,944 f
    ushort_t* h3b = (ushort_t*)(ws + 17694720);    //  7,077,888 u =  3,538,944 f
    ushort_t* h4b = (ushort_t*)(ws + 21233664);    //  1,769,472 u =    884,736 f
    float* h5 = ws + 22118400;                     //  1,769,472 f
    float* m2 = ws + 23887872;                     //    221,184 f
    float* m3 = ws + 24109056;                     //     27,648 f
    float* partials = ws + 24136704;               //      6,912 f
    ushort_t* wp1 = (ushort_t*)(ws + 24143616);    //     512 u =    256 f
    ushort_t* wp2 = (ushort_t*)(ws + 24143872);    //  14,336 u =  7,168 f
    ushort_t* wp3 = (ushort_t*)(ws + 24151040);    //  27,648 u = 13,824 f
    ushort_t* wp4 = (ushort_t*)(ws + 24164864);    //  55,296 u = 27,648 f
    ushort_t* wp5 = (ushort_t*)(ws + 24192512);    // 110,592 u = 55,296 f
    float* zeropad = ws + 24247808;                //          8 f (32B zero block)
    int* counters = (int*)(ws + 24247816);         //  64 counters x 32-int stride
    // active-voxel list ALIASES h2b region (consumed before conv2 writes h2b):
    // 64 partitions x 27,648 ints = 1,769,472 ints = 7 MB
    int* list = (int*)(ws + 14155776);

    prep_k<<<1687, 256, 0, stream>>>(w1, w2, w3, w4, w5, m1,
                                     wp1, wp2, wp3, wp4, wp5, m2, zeropad, counters);
    dmask_k<24, 48><<<108, 256, 0, stream>>>(m2, m3);

    const ushort_t* zp = (const ushort_t*)zeropad;
    // layer 1: zero-fill + 64-partition compact, then active-only MFMA
    conv1_fill_k<<<6912, 256, 0, stream>>>(m1, h1b, list, counters);
    conv1_act_k<<<864, 256, 0, stream>>>(x, list, counters, wp1, b1, g1, zeropad, h1b);
    // layer 2: halo-tile LDS MFMA + fused norm
    conv2_tile_k<<<3456, 256, 0, stream>>>(h1b, wp2, b2, g2, m2, zp, h2b);
    // layer 3: halo-tile LDS MFMA + fused norm
    conv3_tile_k<<<3456, 256, 0, stream>>>(h2b, wp3, b3, g3, m2, zp, h3b);
    // layer 4/5: halo-tile LDS MFMA + fused 64-ch norm
    conv45_tile_k<48, 32, 2, true><<<1728, 256, 0, stream>>>(h3b, wp4, b4, g4, m3, h4b, nullptr);
    conv45_tile_k<24, 64, 1, false><<<1728, 256, 0, stream>>>(h4b, wp5, b5, g5, m3, nullptr, h5);

    // pool + head
    pool1_k<<<108, 256, 0, stream>>>(h5, partials);
    pool2_head_k<<<1, 128, 0, stream>>>(partials, wh, bh, gh, out);
}

// Round 11
// 237.136 us; speedup vs baseline: 2.2831x; 1.0293x over previous
//
#include <hip/hip_runtime.h>
#include <math.h>

#define K_ADA 0.1f
#define NEPS 1e-5f

typedef __attribute__((ext_vector_type(8))) short short8;
typedef __attribute__((ext_vector_type(4))) float f32x4;
typedef unsigned short ushort_t;

__device__ __forceinline__ ushort_t f2b(float f) {
    union { float f; unsigned u; } v; v.f = f;
    unsigned r = (v.u + 0x7fffu + ((v.u >> 16) & 1u)) >> 16;
    return (ushort_t)r;
}

__device__ __forceinline__ float wave_sum64(float v) {
#pragma unroll
    for (int m = 1; m < 64; m <<= 1) v += __shfl_xor(v, m, 64);
    return v;
}

// tap -> halo delta (stride-2 input, 9x9 plane): kd*81 + kh*9 + kw
__host__ __device__ constexpr int tapd2(int tap) {
    return tap >= 27 ? 0 : (tap / 9) * 81 + ((tap / 3) % 3) * 9 + (tap % 3);
}

// ---- generic pack element: [3,3,3,CIN,COUT] fp32 -> B-fragment bf16 ----
template <int CIN, int COUT>
__device__ __forceinline__ void pack_w_el(const float* __restrict__ w,
                                          ushort_t* __restrict__ wp, int t)
{
    constexpr int NKH = CIN / 32;
    constexpr int NCT = COUT / 16;
    int jj = t & 7;
    int lane = (t >> 3) & 63;
    int rest = t >> 9;              // (tap*NCT + ct)*NKH + kh
    int kh = rest % NKH;
    int rest2 = rest / NKH;
    int ct = rest2 % NCT;
    int tap = rest2 / NCT;
    int cin = kh * 32 + (lane >> 4) * 8 + jj;
    int cout = ct * 16 + (lane & 15);
    wp[t] = f2b(w[(tap * CIN + cin) * COUT + cout]);
}

// ---- merged prep: packs + dmask m1->m2 + zero-pad + counters + pooled init ----
__global__ __launch_bounds__(256) void prep_k(
    const float* __restrict__ w1, const float* __restrict__ w2,
    const float* __restrict__ w3, const float* __restrict__ w4,
    const float* __restrict__ w5, const float* __restrict__ m1,
    ushort_t* __restrict__ wp1, ushort_t* __restrict__ wp2,
    ushort_t* __restrict__ wp3, ushort_t* __restrict__ wp4,
    ushort_t* __restrict__ wp5, float* __restrict__ m2,
    float* __restrict__ zeropad, int* __restrict__ counters,
    float* __restrict__ pooled)
{
    int t = blockIdx.x * 256 + threadIdx.x;
    if (t < 512) {
        int jj = t & 7;
        int lane = t >> 3;
        int tap = (lane >> 4) * 8 + jj;
        int cout = lane & 15;
        wp1[t] = (tap < 27) ? f2b(w1[tap * 16 + cout]) : (ushort_t)0;
    } else if (t < 14848) {
        int u = t - 512;
        int jj = u & 7;
        int lane = (u >> 3) & 63;
        int rest = u >> 9;
        int ct = rest & 1;
        int p = rest >> 1;
        int tap = 2 * p + (lane >> 5);
        int cin = ((lane >> 4) & 1) * 8 + jj;
        int cout = ct * 16 + (lane & 15);
        wp2[u] = (tap < 27) ? f2b(w2[(tap * 16 + cin) * 32 + cout]) : (ushort_t)0;
    } else if (t < 42496) {
        pack_w_el<32, 32>(w3, wp3, t - 14848);
    } else if (t < 97792) {
        pack_w_el<32, 64>(w4, wp4, t - 42496);
    } else if (t < 208384) {
        pack_w_el<64, 64>(w5, wp5, t - 97792);
    } else if (t < 429568) {
        // dmask 96 -> 48
        int v = t - 208384;
        constexpr int GO = 48, GI = 96;
        int b = v / (GO * GO * GO);
        int r = v % (GO * GO * GO);
        int d = r / (GO * GO), h = (r / GO) % GO, x = r % GO;
        float mx = 0.f;
        for (int kd = 0; kd < 3; ++kd) {
            int zd = 2 * d + kd - 1; if ((unsigned)zd >= GI) continue;
            for (int kh = 0; kh < 3; ++kh) {
                int zh = 2 * h + kh - 1; if ((unsigned)zh >= GI) continue;
                for (int kw = 0; kw < 3; ++kw) {
                    int zx = 2 * x + kw - 1; if ((unsigned)zx >= GI) continue;
                    mx = fmaxf(mx, m1[((b * GI + zd) * GI + zh) * GI + zx]);
                }
            }
        }
        m2[v] = mx;
    } else if (t < 429576) {
        zeropad[t - 429568] = 0.f;
    } else if (t < 431624) {
        counters[t - 429576] = 0;   // 64 counters, 128B-spaced
    } else if (t < 431752) {
        pooled[t - 431624] = 0.f;   // 2x64 pooled accumulators (atomicMax targets)
    }
}

// downsample mask m2 -> m3
template <int GO, int GI>
__global__ __launch_bounds__(256) void dmask_k(const float* __restrict__ mi,
                                               float* __restrict__ mo)
{
    constexpr int N = 2 * GO * GO * GO;
    int v = blockIdx.x * 256 + threadIdx.x;
    if (v >= N) return;
    int b = v / (GO * GO * GO);
    int r = v % (GO * GO * GO);
    int d = r / (GO * GO), h = (r / GO) % GO, x = r % GO;
    float mx = 0.f;
    for (int kd = 0; kd < 3; ++kd) {
        int zd = 2 * d + kd - 1; if ((unsigned)zd >= GI) continue;
        for (int kh = 0; kh < 3; ++kh) {
            int zh = 2 * h + kh - 1; if ((unsigned)zh >= GI) continue;
            for (int kw = 0; kw < 3; ++kw) {
                int zx = 2 * x + kw - 1; if ((unsigned)zx >= GI) continue;
                mx = fmaxf(mx, mi[((b * GI + zd) * GI + zh) * GI + zx]);
            }
        }
    }
    mo[v] = mx;
}

// ---- conv1 stage A: zero-fill h1b + compact actives into 64 partitions ----
__global__ __launch_bounds__(256) void conv1_fill_k(const float* __restrict__ m1,
                                                    ushort_t* __restrict__ h1b,
                                                    int* __restrict__ list,
                                                    int* __restrict__ counters)
{
    int v = blockIdx.x * 256 + threadIdx.x;
    const short8 z = {0, 0, 0, 0, 0, 0, 0, 0};
    short8* hp = reinterpret_cast<short8*>(h1b + (size_t)v * 16);
    hp[0] = z; hp[1] = z;
    bool act = (m1[v] != 0.f);
    unsigned long long msk = __ballot(act);
    int lane = threadIdx.x & 63;
    int gwave = v >> 6;
    int p = gwave & 63;
    int base = 0;
    int cnt = __popcll(msk);
    if (lane == 0 && cnt) base = atomicAdd(&counters[p * 32], cnt);
    base = __shfl(base, 0, 64);
    if (act) {
        int pre = __popcll(msk & ((1ull << lane) - 1ull));
        list[p * 27648 + base + pre] = v;
    }
}

// ---- conv1 stage B: MFMA over ACTIVE voxels only ----
__global__ __launch_bounds__(256) void conv1_act_k(const float* __restrict__ x,
                                                   const int* __restrict__ list,
                                                   const int* __restrict__ counters,
                                                   const ushort_t* __restrict__ wp1,
                                                   const float* __restrict__ bias,
                                                   const float* __restrict__ gain,
                                                   const float* __restrict__ zerof,
                                                   ushort_t* __restrict__ h1b)
{
    constexpr int G = 96, G3 = G * G * G;
    int gwave = (blockIdx.x * 256 + threadIdx.x) >> 6;
    int p = gwave & 63;
    int lw = gwave >> 6;
    int nact = counters[p * 32];
    if (nact <= 0) return;
    const int* plist = list + p * 27648;
    int lane = threadIdx.x & 63;
    int m = lane & 15, q = lane >> 4;
    int nchunk = (nact + 15) >> 4;
    float bn = bias[m], gn = gain[m];
    short8 bfr = *reinterpret_cast<const short8*>(wp1 + lane * 8);

    for (int chunk = lw; chunk < nchunk; chunk += 54) {
        int idx = chunk * 16 + m;
        int vm = plist[min(idx, nact - 1)];
        int b = vm / G3;
        int rr = vm % G3;
        int dm = rr / (G * G), hm = (rr / G) % G, xm = rr % G;

        float xs[8];
#pragma unroll
        for (int j = 0; j < 8; ++j) {
            int k = q * 8 + j;
            int kd = k / 9, kh = (k / 3) % 3, kw = k % 3;
            int id = dm + kd - 1, ih = hm + kh - 1, ix = xm + kw - 1;
            bool ok = (k < 27) && ((unsigned)id < (unsigned)G) &&
                      ((unsigned)ih < (unsigned)G) && ((unsigned)ix < (unsigned)G);
            const float* xp = ok ? (x + (((size_t)b * G + id) * G + ih) * G + ix) : zerof;
            xs[j] = *xp;
        }
        ushort_t av[8];
#pragma unroll
        for (int j = 0; j < 8; ++j) av[j] = f2b(xs[j]);
        short8 a = *reinterpret_cast<short8*>(av);
        f32x4 acc = {0.f, 0.f, 0.f, 0.f};
        acc = __builtin_amdgcn_mfma_f32_16x16x32_bf16(a, bfr, acc, 0, 0, 0);

#pragma unroll
        for (int i = 0; i < 4; ++i) {
            int oidx = chunk * 16 + q * 4 + i;
            float xv = acc[i] + bn;
            float s = xv;
#pragma unroll
            for (int mk = 1; mk < 16; mk <<= 1) s += __shfl_xor(s, mk, 64);
            float mean = s * (1.f / 16.f);
            float dd = xv - mean;
            float ss = dd * dd;
#pragma unroll
            for (int mk = 1; mk < 16; mk <<= 1) ss += __shfl_xor(ss, mk, 64);
            float rs = rsqrtf(ss * (1.f / 16.f) + NEPS);
            float xn = dd * rs;
            float o = fmaxf(gn * (1.f - K_ADA * xn) * xn, 0.f);
            if (oidx < nact) {
                int w = plist[oidx];
                h1b[(size_t)w * 16 + m] = f2b(o);
            }
        }
    }
}

// ---- layer 2: halo-tile MFMA, A-read dedup (A shared across both cts) ----
__global__ __launch_bounds__(256, 4) void conv2_tile_k(
    const ushort_t* __restrict__ h1b, const ushort_t* __restrict__ wp2,
    const float* __restrict__ bias, const float* __restrict__ gain,
    const float* __restrict__ m2, const ushort_t* __restrict__ zp,
    ushort_t* __restrict__ h2b)
{
    constexpr int GI = 96, G = 48;
    __shared__ __align__(16) ushort_t halo[729 * 3 * 8];

    int bid = blockIdx.x;
    int b = bid / 1728;
    int r = bid % 1728;
    int td = r / 144, th = (r / 12) % 12, tx = r % 12;
    int d0 = 4 * td, h0 = 4 * th, x0 = 4 * tx;
    int bd = 2 * d0 - 1, bh = 2 * h0 - 1, bx = 2 * x0 - 1;

    for (int c = threadIdx.x; c < 1458; c += 256) {
        int hv = c >> 1, j = c & 1;
        int gd = bd + hv / 81;
        int gh = bh + (hv / 9) % 9;
        int gx = bx + hv % 9;
        bool ok = ((unsigned)gd < (unsigned)GI) && ((unsigned)gh < (unsigned)GI) &&
                  ((unsigned)gx < (unsigned)GI);
        const ushort_t* p = ok ? (h1b + ((((size_t)b * GI + gd) * GI + gh) * GI + gx) * 16 + j * 8) : zp;
        *reinterpret_cast<short8*>(halo + ((size_t)hv * 3 + j) * 8) =
            *reinterpret_cast<const short8*>(p);
    }
    __syncthreads();

    int wv = threadIdx.x >> 6;   // wave = output d-slice
    int lane = threadIdx.x & 63;
    int m = lane & 15, q = lane >> 4;
    int mh = m >> 2, mx = m & 3;
    int tq = q >> 1, hq = q & 1;
    int hbase = 162 * wv + 18 * mh + 2 * mx;

    f32x4 acc0 = {0.f, 0.f, 0.f, 0.f}, acc1 = acc0;
#pragma unroll
    for (int g = 0; g < 2; ++g) {
        short8 a[7], b0[7], b1[7];
#pragma unroll
        for (int j = 0; j < 7; ++j) {
            const int p = g * 7 + j;
            int hv = hbase + (tq ? tapd2(2 * p + 1) : tapd2(2 * p));
            a[j] = *reinterpret_cast<const short8*>(halo + ((size_t)hv * 3 + hq) * 8);
            b0[j] = *reinterpret_cast<const short8*>(wp2 + ((size_t)(p * 2 + 0) * 64 + lane) * 8);
            b1[j] = *reinterpret_cast<const short8*>(wp2 + ((size_t)(p * 2 + 1) * 64 + lane) * 8);
        }
#pragma unroll
        for (int j = 0; j < 7; ++j) {
            acc0 = __builtin_amdgcn_mfma_f32_16x16x32_bf16(a[j], b0[j], acc0, 0, 0, 0);
            acc1 = __builtin_amdgcn_mfma_f32_16x16x32_bf16(a[j], b1[j], acc1, 0, 0, 0);
        }
    }

    float b0s = bias[m], b1s = bias[16 + m];
    float g0s = gain[m], g1s = gain[16 + m];
#pragma unroll
    for (int i = 0; i < 4; ++i) {
        int rr2 = q * 4 + i;
        int w = ((b * G + d0 + wv) * G + h0 + (rr2 >> 2)) * G + x0 + (rr2 & 3);
        float xv0 = acc0[i] + b0s;
        float xv1 = acc1[i] + b1s;
        float s = xv0 + xv1;
#pragma unroll
        for (int mk = 1; mk < 16; mk <<= 1) s += __shfl_xor(s, mk, 64);
        float mean = s * (1.f / 32.f);
        float dd0 = xv0 - mean, dd1 = xv1 - mean;
        float ss = dd0 * dd0 + dd1 * dd1;
#pragma unroll
        for (int mk = 1; mk < 16; mk <<= 1) ss += __shfl_xor(ss, mk, 64);
        float rs = rsqrtf(ss * (1.f / 32.f) + NEPS);
        float mv = m2[w];
        float xn0 = dd0 * rs, xn1 = dd1 * rs;
        float o0 = fmaxf(g0s * (1.f - K_ADA * xn0) * xn0, 0.f);
        float o1 = fmaxf(g1s * (1.f - K_ADA * xn1) * xn1, 0.f);
        if (mv == 0.f) { o0 = 0.f; o1 = 0.f; }
        h2b[(size_t)w * 32 + m]      = f2b(o0);
        h2b[(size_t)w * 32 + 16 + m] = f2b(o1);
    }
}

// ---- layer 3: halo-tile MFMA, CT-SPLIT waves (halves B traffic) ----
// Wave wv: ct = wv&1, slice-pair sp = wv>>1 (d-slices 2sp, 2sp+1).
// Norm via LDS nbuf (cross-wave: couts of a voxel span 2 waves).
__global__ __launch_bounds__(256, 3) void conv3_tile_k(
    const ushort_t* __restrict__ h2b, const ushort_t* __restrict__ wp3,
    const float* __restrict__ bias, const float* __restrict__ gain,
    const float* __restrict__ m2, const ushort_t* __restrict__ zp,
    ushort_t* __restrict__ h3b)
{
    constexpr int G = 48;
    __shared__ __align__(16) ushort_t halo[216 * 5 * 8];
    __shared__ float nbuf[64][33];

    int bid = blockIdx.x;
    int b = bid / 1728;
    int r = bid % 1728;
    int td = r / 144, th = (r / 12) % 12, tx = r % 12;
    int d0 = 4 * td, h0 = 4 * th, x0 = 4 * tx;
    int bd = d0 - 1, bh = h0 - 1, bx = x0 - 1;

    for (int c = threadIdx.x; c < 864; c += 256) {
        int hv = c >> 2, j = c & 3;
        int gd = bd + hv / 36;
        int gh = bh + (hv / 6) % 6;
        int gx = bx + hv % 6;
        bool ok = ((unsigned)gd < (unsigned)G) && ((unsigned)gh < (unsigned)G) &&
                  ((unsigned)gx < (unsigned)G);
        const ushort_t* p = ok ? (h2b + ((((size_t)b * G + gd) * G + gh) * G + gx) * 32 + j * 8) : zp;
        *reinterpret_cast<short8*>(halo + ((size_t)hv * 5 + j) * 8) =
            *reinterpret_cast<const short8*>(p);
    }
    __syncthreads();

    int wv = threadIdx.x >> 6;
    int lane = threadIdx.x & 63;
    int m = lane & 15, q = lane >> 4;
    int mh = m >> 2, mx = m & 3;
    int ct = wv & 1;
    int sp = wv >> 1;
    int hb0 = 36 * (2 * sp) + 6 * mh + mx;   // slice 2sp
    int hb1 = hb0 + 36;                      // slice 2sp+1

    f32x4 acc0 = {0.f, 0.f, 0.f, 0.f}, acc1 = acc0;
#pragma unroll
    for (int g = 0; g < 3; ++g) {
        short8 a0[9], a1[9], bb[9];
#pragma unroll
        for (int j = 0; j < 9; ++j) {
            const int tap = g * 9 + j;
            const int dlt = (tap / 9) * 36 + ((tap / 3) % 3) * 6 + (tap % 3);
            a0[j] = *reinterpret_cast<const short8*>(halo + ((size_t)(hb0 + dlt) * 5 + q) * 8);
            a1[j] = *reinterpret_cast<const short8*>(halo + ((size_t)(hb1 + dlt) * 5 + q) * 8);
            bb[j] = *reinterpret_cast<const short8*>(
                wp3 + ((size_t)(tap * 2 + ct) * 64 + lane) * 8);
        }
#pragma unroll
        for (int j = 0; j < 9; ++j) {
            acc0 = __builtin_amdgcn_mfma_f32_16x16x32_bf16(a0[j], bb[j], acc0, 0, 0, 0);
            acc1 = __builtin_amdgcn_mfma_f32_16x16x32_bf16(a1[j], bb[j], acc1, 0, 0, 0);
        }
    }

    // scatter conv+bias to nbuf: voxel rows 0..63 (slice*16 + rr2), col = ct*16+m
    float bn = bias[ct * 16 + m];
#pragma unroll
    for (int i = 0; i < 4; ++i) {
        int rr2 = q * 4 + i;
        nbuf[(2 * sp) * 16 + rr2][ct * 16 + m]     = acc0[i] + bn;
        nbuf[(2 * sp + 1) * 16 + rr2][ct * 16 + m] = acc1[i] + bn;
    }
    __syncthreads();

    // norm: wave wv handles voxels [wv*16, wv*16+16), 2 per iter (32-lane groups)
    int hh = lane >> 5;
    int ch = lane & 31;
    float gns = gain[ch];
    float bswap; (void)bswap;
#pragma unroll
    for (int it = 0; it < 8; ++it) {
        int vloc = wv * 16 + it * 2 + hh;
        float val = nbuf[vloc][ch];
        float s = val;
#pragma unroll
        for (int mk = 1; mk < 32; mk <<= 1) s += __shfl_xor(s, mk, 64);
        float mean = s * (1.f / 32.f);
        float dd = val - mean;
        float ss = dd * dd;
#pragma unroll
        for (int mk = 1; mk < 32; mk <<= 1) ss += __shfl_xor(ss, mk, 64);
        float rs = rsqrtf(ss * (1.f / 32.f) + NEPS);
        int slice = vloc >> 4, rr2 = vloc & 15;
        int w = ((b * G + d0 + slice) * G + h0 + (rr2 >> 2)) * G + x0 + (rr2 & 3);
        float xn = dd * rs;
        float o = fmaxf(gns * (1.f - K_ADA * xn) * xn, 0.f);
        if (m2[w] == 0.f) o = 0.f;
        h3b[(size_t)w * 32 + ch] = f2b(o);
    }
}

// ---- layers 4/5: HALO-TILE implicit GEMM; l5 fuses global max pool ----
template <int G_IN, int CIN, int STRIDE, bool POOL>
__global__ __launch_bounds__(256, 4) void conv45_tile_k(
    const ushort_t* __restrict__ Ab, const ushort_t* __restrict__ Wp,
    const float* __restrict__ bias, const float* __restrict__ gain,
    const float* __restrict__ mask,
    ushort_t* __restrict__ outb, unsigned* __restrict__ pooled)
{
    constexpr int G = 24;
    constexpr int NKH = CIN / 32;
    constexpr int NCH = CIN / 8;
    constexpr int PADC = NCH + 1;
    constexpr int HD = STRIDE + 3;
    constexpr int HH = STRIDE + 3;
    constexpr int HX = 3 * STRIDE + 3;
    constexpr int NHV = HD * HH * HX;
    constexpr int NCHUNK = NHV * NCH;

    __shared__ __align__(16) ushort_t halo[NHV * PADC * 8];
    __shared__ float nbuf[16][65];
    __shared__ float pbuf[4][64];

    int bid = blockIdx.x;
    int b = bid / 864;
    int r = bid % 864;
    int td = r / 72, th = (r / 6) % 12, tx = r % 6;
    int d0 = 2 * td, h0 = 2 * th, x0 = 4 * tx;
    int bd = d0 * STRIDE - 1, bh = h0 * STRIDE - 1, bx = x0 * STRIDE - 1;

    for (int c = threadIdx.x; c < NCHUNK; c += 256) {
        int hv = c / NCH, j = c % NCH;
        int gd = bd + hv / (HH * HX);
        int gh = bh + (hv / HX) % HH;
        int gx = bx + hv % HX;
        short8 val = {0, 0, 0, 0, 0, 0, 0, 0};
        if ((unsigned)gd < (unsigned)G_IN && (unsigned)gh < (unsigned)G_IN &&
            (unsigned)gx < (unsigned)G_IN)
            val = *reinterpret_cast<const short8*>(
                Ab + ((((size_t)b * G_IN + gd) * G_IN + gh) * G_IN + gx) * CIN + j * 8);
        *reinterpret_cast<short8*>(halo + ((size_t)hv * PADC + j) * 8) = val;
    }
    __syncthreads();

    int ct = threadIdx.x >> 6;
    int lane = threadIdx.x & 63;
    int m = lane & 15, q = lane >> 4;
    int md = (m >> 3) & 1, mh = (m >> 2) & 1, mx = m & 3;

    f32x4 acc = {0.f, 0.f, 0.f, 0.f};
    constexpr int NT = 27 * NKH;
    constexpr int GSZ = 9;
#pragma unroll
    for (int g = 0; g < NT / GSZ; ++g) {
        short8 ab[GSZ], bb[GSZ];
#pragma unroll
        for (int j = 0; j < GSZ; ++j) {
            int it = g * GSZ + j;
            int tap = it / NKH, k2 = it % NKH;
            const int kd = tap / 9, kh = (tap / 3) % 3, kw = tap % 3;
            int hv = ((md * STRIDE + kd) * HH + (mh * STRIDE + kh)) * HX +
                     (mx * STRIDE + kw);
            ab[j] = *reinterpret_cast<const short8*>(
                halo + ((size_t)hv * PADC + k2 * 4 + q) * 8);
            bb[j] = *reinterpret_cast<const short8*>(
                Wp + (((size_t)(tap * 4 + ct) * NKH + k2) * 64 + lane) * 8);
        }
#pragma unroll
        for (int j = 0; j < GSZ; ++j)
            acc = __builtin_amdgcn_mfma_f32_16x16x32_bf16(ab[j], bb[j], acc, 0, 0, 0);
    }

    float bn = bias[ct * 16 + m];
#pragma unroll
    for (int i = 0; i < 4; ++i) nbuf[q * 4 + i][ct * 16 + m] = acc[i] + bn;
    __syncthreads();

    float gn = gain[lane];
    float wavemax = 0.f;
#pragma unroll
    for (int i = 0; i < 4; ++i) {
        int vloc = ct * 4 + i;
        int vd = d0 + ((vloc >> 3) & 1);
        int vh = h0 + ((vloc >> 2) & 1);
        int vx = x0 + (vloc & 3);
        int w = ((b * G + vd) * G + vh) * G + vx;
        float val = nbuf[vloc][lane];
        float mean = wave_sum64(val) * (1.f / 64.f);
        float dd = val - mean;
        float var = wave_sum64(dd * dd) * (1.f / 64.f) + NEPS;
        float xn = dd * rsqrtf(var);
        float o = fmaxf(gn * (1.f - K_ADA * xn) * xn, 0.f);
        if (mask[w] == 0.f) o = 0.f;
        if (POOL) wavemax = fmaxf(wavemax, o);
        else      outb[(size_t)w * 64 + lane] = f2b(o);
    }
    if (POOL) {
        pbuf[ct][lane] = wavemax;
        __syncthreads();
        if (ct == 0) {
            float v = fmaxf(fmaxf(pbuf[0][lane], pbuf[1][lane]),
                            fmaxf(pbuf[2][lane], pbuf[3][lane]));
            // o >= 0 so float bit pattern is monotone under unsigned max
            atomicMax(&pooled[b * 64 + lane], __float_as_uint(v));
        }
    }
}

// ---- head: reads pooled (float bits), GEMV + AdaNorm + ReLU ----
__global__ __launch_bounds__(128) void head_k(const float* __restrict__ pooled,
                                              const float* __restrict__ wh,
                                              const float* __restrict__ bh,
                                              const float* __restrict__ gh,
                                              float* __restrict__ out)
{
    __shared__ float pl[2][64];
    int t = threadIdx.x;
    int b = t >> 6;
    int f = t & 63;
    pl[b][f] = pooled[b * 64 + f];
    __syncthreads();
    float acc = bh[f];
#pragma unroll
    for (int k = 0; k < 64; ++k) acc += pl[b][k] * wh[k * 64 + f];
    float mean = wave_sum64(acc) * (1.f / 64.f);
    float dd = acc - mean;
    float var = wave_sum64(dd * dd) * (1.f / 64.f) + NEPS;
    float xn = dd * rsqrtf(var);
    float val = gh[f] * (1.f - K_ADA * xn) * xn;
    out[t] = fmaxf(val, 0.f);
}

extern "C" void kernel_launch(void* const* d_in, const int* in_sizes, int n_in,
                              void* d_out, int out_size, void* d_ws, size_t ws_size,
                              hipStream_t stream)
{
    const float* x  = (const float*)d_in[0];
    const float* m1 = (const float*)d_in[1];
    const float* w1 = (const float*)d_in[2];
    const float* b1 = (const float*)d_in[3];
    const float* g1 = (const float*)d_in[4];
    const float* w2 = (const float*)d_in[5];
    const float* b2 = (const float*)d_in[6];
    const float* g2 = (const float*)d_in[7];
    const float* w3 = (const float*)d_in[8];
    const float* b3 = (const float*)d_in[9];
    const float* g3 = (const float*)d_in[10];
    const float* w4 = (const float*)d_in[11];
    const float* b4 = (const float*)d_in[12];
    const float* g4 = (const float*)d_in[13];
    const float* w5 = (const float*)d_in[14];
    const float* b5 = (const float*)d_in[15];
    const float* g5 = (const float*)d_in[16];
    const float* wh = (const float*)d_in[17];
    const float* bh = (const float*)d_in[18];
    const float* gh = (const float*)d_in[19];
    float* out = (float*)d_out;

    // workspace layout (float units; all 16B aligned)
    float* ws = (float*)d_ws;
    ushort_t* h1b = (ushort_t*)ws;                 // 28,311,552 u = 14,155,776 f
    ushort_t* h2b = (ushort_t*)(ws + 14155776);    //  7,077,888 u =  3,538,944 f
    ushort_t* h3b = (ushort_t*)(ws + 17694720);    //  7,077,888 u =  3,538,944 f
    ushort_t* h4b = (ushort_t*)(ws + 21233664);    //  1,769,472 u =    884,736 f
    float* m2 = ws + 22118400;                     //    221,184 f
    float* m3 = ws + 22339584;                     //     27,648 f
    ushort_t* wp1 = (ushort_t*)(ws + 22367232);    //     512 u =    256 f
    ushort_t* wp2 = (ushort_t*)(ws + 22367488);    //  14,336 u =  7,168 f
    ushort_t* wp3 = (ushort_t*)(ws + 22374656);    //  27,648 u = 13,824 f
    ushort_t* wp4 = (ushort_t*)(ws + 22388480);    //  55,296 u = 27,648 f
    ushort_t* wp5 = (ushort_t*)(ws + 22416128);    // 110,592 u = 55,296 f
    float* zeropad = ws + 22471424;                //          8 f
    int* counters = (int*)(ws + 22471432);         //  2048 ints (64 x 128B-spaced)
    float* pooled = ws + 22473480;                 //        128 f (atomicMax targets)
    // active-voxel list ALIASES h2b region (consumed before conv2 writes h2b)
    int* list = (int*)(ws + 14155776);

    prep_k<<<1687, 256, 0, stream>>>(w1, w2, w3, w4, w5, m1,
                                     wp1, wp2, wp3, wp4, wp5, m2, zeropad,
                                     counters, pooled);
    dmask_k<24, 48><<<108, 256, 0, stream>>>(m2, m3);

    const ushort_t* zp = (const ushort_t*)zeropad;
    conv1_fill_k<<<6912, 256, 0, stream>>>(m1, h1b, list, counters);
    conv1_act_k<<<864, 256, 0, stream>>>(x, list, counters, wp1, b1, g1, zeropad, h1b);
    conv2_tile_k<<<3456, 256, 0, stream>>>(h1b, wp2, b2, g2, m2, zp, h2b);
    conv3_tile_k<<<3456, 256, 0, stream>>>(h2b, wp3, b3, g3, m2, zp, h3b);
    conv45_tile_k<48, 32, 2, false><<<1728, 256, 0, stream>>>(h3b, wp4, b4, g4, m3, h4b, nullptr);
    conv45_tile_k<24, 64, 1, true><<<1728, 256, 0, stream>>>(h4b, wp5, b5, g5, m3, nullptr,
                                                             (unsigned*)pooled);
    head_k<<<1, 128, 0, stream>>>(pooled, wh, bh, gh, out);
}